// Round 12
// baseline (997.160 us; speedup 1.0000x reference)
//
#include <hip/hip_runtime.h>

typedef unsigned short ushortT;
typedef __attribute__((ext_vector_type(4))) float f32x4;
typedef __attribute__((ext_vector_type(8))) short bf16x8;
typedef __attribute__((ext_vector_type(4))) unsigned int u32x4;
typedef __attribute__((ext_vector_type(4))) unsigned short u16x4;

#define N_ATOMS 6000
#define NSUB    20000
#define NEDGE   60000
#define NBATCH  16
#define INDIM   78
#define EMB     1024
#define HID     2048
#define NH      4
#define CH      512
#define NL      3
#define MP      20096          // NSUB padded to multiple of 128
#define AP      6016           // N_ATOMS padded to multiple of 128
#define ETOT    (NEDGE + NSUB) // edges + self loops
#define NPB     8              // atoms per block in k_node_proj

#define GLOAD_LDS16(gp, lp) \
    __builtin_amdgcn_global_load_lds((const __attribute__((address_space(1))) void*)(gp), \
                                     (__attribute__((address_space(3))) void*)(lp), 16, 0, 0)

__device__ __forceinline__ ushortT f2bf(float x) {
    union { float f; unsigned u; } v; v.f = x;
    unsigned r = v.u + 0x7fffu + ((v.u >> 16) & 1u);   // RNE
    return (ushortT)(r >> 16);
}
__device__ __forceinline__ float bf2f(ushortT h) {
    union { unsigned u; float f; } v; v.u = ((unsigned)h) << 16; return v.f;
}

// ---------- weight cast + transpose: W[K,N] f32 -> Wt[N,K] bf16 ----------
__global__ void k_cast_transpose(const float* __restrict__ W, ushortT* __restrict__ Wt,
                                 int K, int Nn) {
    __shared__ float tile[32][33];
    int n0 = blockIdx.x * 32, k0 = blockIdx.y * 32;
    int tx = threadIdx.x, ty = threadIdx.y; // 32 x 8
    for (int i = 0; i < 32; i += 8)
        tile[ty + i][tx] = W[(size_t)(k0 + ty + i) * Nn + n0 + tx];
    __syncthreads();
    for (int i = 0; i < 32; i += 8)
        Wt[(size_t)(n0 + ty + i) * K + k0 + tx] = f2bf(tile[tx][ty + i]);
}

// ---------- node projection: xpb = bf16(x @ Wn + bn), 8 atoms/block ----------
__global__ __launch_bounds__(256) void k_node_proj(const float* __restrict__ x,
                                                   const float* __restrict__ Wn,
                                                   const float* __restrict__ bn,
                                                   ushortT* __restrict__ xpb) {
    int n0 = blockIdx.x * NPB;
    __shared__ float xr[NPB][INDIM];
    int tid = threadIdx.x;
    for (int i = tid; i < NPB * INDIM; i += 256)
        xr[i / INDIM][i % INDIM] = x[(size_t)(n0 + i / INDIM) * INDIM + (i % INDIM)];
    __syncthreads();
    for (int j = tid; j < EMB; j += 256) {
        float acc[NPB];
        float b = bn[j];
        #pragma unroll
        for (int a = 0; a < NPB; ++a) acc[a] = b;
        #pragma unroll 6
        for (int k = 0; k < INDIM; ++k) {
            float wv = Wn[(size_t)k * EMB + j];
            #pragma unroll
            for (int a = 0; a < NPB; ++a) acc[a] += xr[a][k] * wv;
        }
        #pragma unroll
        for (int a = 0; a < NPB; ++a)
            xpb[(size_t)(n0 + a) * EMB + j] = f2bf(acc[a]);
    }
}

// ---------- mean of edge_attr, pass 1: 64 deterministic partials ----------
__global__ void k_mean_part(const float* __restrict__ ea, float* __restrict__ mpart) {
    __shared__ float red[256];
    int b = blockIdx.x;
    float s = 0;
    for (int i = b * 256 + threadIdx.x; i < NEDGE; i += 64 * 256) s += ea[i];
    red[threadIdx.x] = s; __syncthreads();
    for (int d = 128; d > 0; d >>= 1) {
        if (threadIdx.x < d) red[threadIdx.x] += red[threadIdx.x + d];
        __syncthreads();
    }
    if (threadIdx.x == 0) mpart[b] = red[0];
}

// ---------- per-edge prep: subgraph src, atom src, edge attr (self-loop = mean) ----
__global__ void k_eprep(const int* __restrict__ srci, const int* __restrict__ sni,
                        const float* __restrict__ ea, const float* __restrict__ meana,
                        int* __restrict__ esrcS, int* __restrict__ esrcA,
                        float* __restrict__ eaf) {
    int t = blockIdx.x * 256 + threadIdx.x;
    if (t >= ETOT) return;
    int s = (t < NEDGE) ? srci[t] : (t - NEDGE);
    esrcS[t] = s;
    esrcA[t] = sni[s];
    eaf[t] = (t < NEDGE) ? ea[t] : meana[0];
}

// ---------- edge-attention scalars p,q: split-K partials (12 x 16 blocks) ----------
__global__ __launch_bounds__(256) void k_pq_part(const float* __restrict__ We,
                                                 const float* __restrict__ be,
                                                 const float* __restrict__ W_edge,
                                                 const float* __restrict__ att_edge,
                                                 float* __restrict__ part) {
    int l = blockIdx.x >> 2, h = blockIdx.x & 3;
    int k0 = blockIdx.y * 64;
    const float* Wl = W_edge + (size_t)l * EMB * HID + h * CH;
    const float* ae = att_edge + ((size_t)l * NH + h) * CH;
    int tid = threadIdx.x;
    float aP0 = 0, aP1 = 0, aQ0 = 0, aQ1 = 0;
    #pragma unroll 4
    for (int k = k0; k < k0 + 64; ++k) {
        float wek = We[k], bek = be[k];
        float w0 = Wl[(size_t)k * HID + tid];
        float w1 = Wl[(size_t)k * HID + tid + 256];
        aP0 += wek * w0; aP1 += wek * w1;
        aQ0 += bek * w0; aQ1 += bek * w1;
    }
    float p = aP0 * ae[tid] + aP1 * ae[tid + 256];
    float q = aQ0 * ae[tid] + aQ1 * ae[tid + 256];
    __shared__ float rp[256], rq[256];
    rp[tid] = p; rq[tid] = q; __syncthreads();
    for (int d = 128; d > 0; d >>= 1) {
        if (tid < d) { rp[tid] += rp[tid + d]; rq[tid] += rq[tid + d]; }
        __syncthreads();
    }
    if (tid == 0) {
        part[((size_t)blockIdx.y * 12 + blockIdx.x) * 2]     = rp[0];
        part[((size_t)blockIdx.y * 12 + blockIdx.x) * 2 + 1] = rq[0];
    }
}

// ---------- pq + mean final reduce (fixed order, deterministic) ----------
__global__ void k_pq_red(const float* __restrict__ part, const float* __restrict__ mpart,
                         float* __restrict__ pq, float* __restrict__ meana) {
    int t = threadIdx.x;
    if (t < 24) {
        float s = 0;
        for (int kc = 0; kc < 16; ++kc) s += part[((size_t)kc * 12 + (t >> 1)) * 2 + (t & 1)];
        pq[t] = s;
    }
    if (t == 32) {
        float s = 0;
        for (int i = 0; i < 64; ++i) s += mpart[i];
        meana[0] = s / (float)NEDGE;
    }
}

// ---------- generic CSR build: count / scan / fill ----------
__global__ void k_count(const int* __restrict__ dsti, int* __restrict__ cnt) {
    int t = blockIdx.x * 256 + threadIdx.x;
    if (t >= ETOT) return;
    int d = (t < NEDGE) ? dsti[t] : (t - NEDGE);
    atomicAdd(&cnt[d], 1);
}

// exclusive scan over n counts -> rs[0..n], single 1024-thread block
__global__ void k_scan(const int* __restrict__ cnt, int* __restrict__ rs, int n) {
    __shared__ int part[1024];
    int tid = threadIdx.x;
    const int per = (n + 1023) / 1024;
    int base = tid * per;
    int s = 0;
    for (int i = 0; i < per; ++i) { int idx = base + i; if (idx < n) s += cnt[idx]; }
    part[tid] = s;
    __syncthreads();
    for (int d = 1; d < 1024; d <<= 1) {
        int v = (tid >= d) ? part[tid - d] : 0;
        __syncthreads();
        part[tid] += v;
        __syncthreads();
    }
    int off = part[tid] - s; // exclusive
    for (int i = 0; i < per; ++i) {
        int idx = base + i;
        if (idx < n) { rs[idx] = off; off += cnt[idx]; }
    }
    if (tid == 1023) rs[n] = part[1023];
}

__global__ void k_fill(const int* __restrict__ dsti, const int* __restrict__ rs,
                       int* __restrict__ cursor, int* __restrict__ eids) {
    int t = blockIdx.x * 256 + threadIdx.x;
    if (t >= ETOT) return;
    int d = (t < NEDGE) ? dsti[t] : (t - NEDGE);
    int pos = rs[d] + atomicAdd(&cursor[d], 1);
    eids[pos] = t;
}

// CSR over subgraph_indicator (NSUB -> N_ATOMS)
__global__ void k_count_ind(const int* __restrict__ ind, int* __restrict__ cnt) {
    int i = blockIdx.x * 256 + threadIdx.x;
    if (i < NSUB) atomicAdd(&cnt[ind[i]], 1);
}

__global__ void k_fill_ind(const int* __restrict__ ind, const int* __restrict__ rs,
                           int* __restrict__ cursor, int* __restrict__ ids) {
    int i = blockIdx.x * 256 + threadIdx.x;
    if (i >= NSUB) return;
    int a = ind[i];
    int pos = rs[a] + atomicAdd(&cursor[a], 1);
    ids[pos] = i;
}

// ---------- bf16 MFMA GEMM (r7/r9 version, 869 TF): gload_lds + involution swizzle ----
__global__ __launch_bounds__(256) void k_gemm(const ushortT* __restrict__ A,
                                              const ushortT* __restrict__ Bt,
                                              ushortT* __restrict__ Cb, int K) {
    __shared__ alignas(16) ushortT As[128 * 64];   // 16 KB
    __shared__ alignas(16) ushortT Bs[128 * 64];   // 16 KB
    const int tid = threadIdx.x;
    const int nx = (int)gridDim.x;                 // bm tiles
    const int ny = (int)gridDim.y;                 // 16  (bn tiles)
    int o = (int)blockIdx.y * nx + (int)blockIdx.x;  // dispatch order (bx fast)
    int cpx = (nx * ny) >> 3;                        // blocks per XCD
    int s = (o & 7) * cpx + (o >> 3);                // sequential id within XCD span
    const int bm = s / ny, bn = s % ny;              // bn fast -> A-panel reuse
    const int wave = tid >> 6, lane = tid & 63;
    const int wr = wave >> 1, wc = wave & 1;
    f32x4 acc[4][4] = {};
    const int frow = lane & 15;          // fragment row within 16
    const int cb0  = lane >> 4;          // k col-block 0..3 (8 elems each)
    const ushortT* Ab = A + (size_t)bm * 128 * K;
    const ushortT* Bb = Bt + (size_t)bn * 128 * K;
    const int srow = (lane >> 3);                        // 0..7 within chunk
    const int sswz = (((lane & 7) ^ srow) << 3);         // swizzled elem col
    for (int k0 = 0; k0 < K; k0 += 64) {
        #pragma unroll
        for (int i = 0; i < 4; ++i) {
            int c = wave * 4 + i;                        // chunk 0..15
            int r = c * 8 + srow;                        // tile row 0..127
            GLOAD_LDS16(Ab + (size_t)r * K + k0 + sswz, As + c * 512 + lane * 8);
            GLOAD_LDS16(Bb + (size_t)r * K + k0 + sswz, Bs + c * 512 + lane * 8);
        }
        __syncthreads();
        #pragma unroll
        for (int kk = 0; kk < 64; kk += 32) {
            bf16x8 af[4], bfr[4];
            #pragma unroll
            for (int m = 0; m < 4; ++m) {
                int row = wr * 64 + m * 16 + frow;
                int cb = (kk >> 3) + cb0;
                af[m] = *(const bf16x8*)&As[row * 64 + ((cb ^ (frow & 7)) << 3)];
            }
            #pragma unroll
            for (int n = 0; n < 4; ++n) {
                int row = wc * 64 + n * 16 + frow;
                int cb = (kk >> 3) + cb0;
                bfr[n] = *(const bf16x8*)&Bs[row * 64 + ((cb ^ (frow & 7)) << 3)];
            }
            #pragma unroll
            for (int m = 0; m < 4; ++m)
                #pragma unroll
                for (int n = 0; n < 4; ++n)
                    acc[m][n] = __builtin_amdgcn_mfma_f32_16x16x32_bf16(af[m], bfr[n], acc[m][n], 0, 0, 0);
        }
        __syncthreads();
    }
    const int cr = (lane >> 4) * 4;
    const int cc = lane & 15;
    #pragma unroll
    for (int m = 0; m < 4; ++m)
        #pragma unroll
        for (int n = 0; n < 4; ++n)
            #pragma unroll
            for (int r = 0; r < 4; ++r) {
                size_t row = (size_t)bm * 128 + wr * 64 + m * 16 + cr + r;
                int col = bn * 128 + wc * 64 + n * 16 + cc;
                Cb[row * HID + col] = f2bf(acc[m][n][r]);
            }
}

// ---------- per-(node,head) attention dot scalars (bf16 xh) ----------
__global__ __launch_bounds__(256) void k_sdots(const ushortT* __restrict__ xh,
                                               const float* __restrict__ att_src,
                                               const float* __restrict__ att_dst,
                                               float* __restrict__ ssrc,
                                               float* __restrict__ sdst, int layer) {
    int n = blockIdx.x;
    int h = threadIdx.x >> 6, lane = threadIdx.x & 63;
    const ushortT* row = xh + (size_t)n * HID + h * CH + lane * 8;
    const float* as = att_src + ((size_t)layer * NH + h) * CH + lane * 8;
    const float* ad = att_dst + ((size_t)layer * NH + h) * CH + lane * 8;
    u16x4 v0 = *(const u16x4*)row, v1 = *(const u16x4*)(row + 4);
    f32x4 a0 = *(const f32x4*)as, a1 = *(const f32x4*)(as + 4);
    f32x4 d0 = *(const f32x4*)ad, d1 = *(const f32x4*)(ad + 4);
    float ps = 0.f, pd = 0.f;
    #pragma unroll
    for (int t = 0; t < 4; ++t) {
        float f0 = bf2f(v0[t]), f1 = bf2f(v1[t]);
        ps += f0 * a0[t] + f1 * a1[t];
        pd += f0 * d0[t] + f1 * d1[t];
    }
    #pragma unroll
    for (int d = 32; d > 0; d >>= 1) { ps += __shfl_down(ps, d); pd += __shfl_down(pd, d); }
    if (lane == 0) { ssrc[n * NH + h] = ps; sdst[n * NH + h] = pd; }
}

// ---------- fused attention: ONE WAVE PER DST (4 dsts/block, no __syncthreads) ----
// Each wave owns all 4 heads of its dst: lane holds 32 channels (facc[4][8]).
// Online softmax per head (same edge order as before); LayerNorm via in-wave
// shfl_xor reduce over the wave's 2048 channels. nmap: layer-0 dst->atom remap.
__global__ __launch_bounds__(256) void k_attn(const ushortT* __restrict__ xh,
                                              const float* __restrict__ ssrc,
                                              const float* __restrict__ sdst,
                                              const int* __restrict__ rs,
                                              const int* __restrict__ eids,
                                              const int* __restrict__ esrc,
                                              const float* __restrict__ eaf,
                                              const float* __restrict__ pq,
                                              const float* __restrict__ conv_bias,
                                              const float* __restrict__ gammav,
                                              const float* __restrict__ betav,
                                              ushortT* __restrict__ hout, int layer,
                                              const int* __restrict__ nmap) {
    int wv = threadIdx.x >> 6, lane = threadIdx.x & 63;
    int n = blockIdx.x * 4 + wv;       // NSUB = 20000 = 5000 blocks * 4 waves, exact
    int nn = nmap ? nmap[n] : n;
    int beg = rs[n], end = rs[n + 1];
    float px[NH], qx[NH], sd[NH], m[NH], z[NH];
    #pragma unroll
    for (int h = 0; h < NH; ++h) {
        px[h] = pq[(layer * NH + h) * 2];
        qx[h] = pq[(layer * NH + h) * 2 + 1];
        sd[h] = sdst[nn * NH + h];
        m[h] = -INFINITY; z[h] = 0.f;
    }
    float facc[NH][8] = {};
    for (int pos = beg; pos < end; ++pos) {
        int t = eids[pos];
        int s = esrc[t];
        float a = eaf[t];
        const ushortT* xr = xh + (size_t)s * HID + lane * 8;
        #pragma unroll
        for (int h = 0; h < NH; ++h) {
            float logit = ssrc[s * NH + h] + sd[h] + a * px[h] + qx[h];
            logit = (logit > 0.f) ? logit : 0.2f * logit;
            float mn = fmaxf(m[h], logit);
            float scale = expf(m[h] - mn);   // 0 when m == -inf
            float w = expf(logit - mn);
            z[h] = z[h] * scale + w;
            bf16x8 u = *(const bf16x8*)(xr + h * CH);
            #pragma unroll
            for (int j = 0; j < 8; ++j)
                facc[h][j] = facc[h][j] * scale + w * bf2f((ushortT)u[j]);
            m[h] = mn;
        }
    }
    // bias + LN stats over the wave's 2048 channels (32 per lane)
    float val[NH][8];
    float s1 = 0.f, s2 = 0.f;
    #pragma unroll
    for (int h = 0; h < NH; ++h) {
        float inv = 1.f / (z[h] + 1e-16f);
        int cb = h * CH + lane * 8;
        f32x4 b0 = *(const f32x4*)&conv_bias[layer * HID + cb];
        f32x4 b1 = *(const f32x4*)&conv_bias[layer * HID + cb + 4];
        #pragma unroll
        for (int j = 0; j < 4; ++j) {
            float v0 = facc[h][j] * inv + b0[j];
            float v1 = facc[h][4 + j] * inv + b1[j];
            val[h][j] = v0; val[h][4 + j] = v1;
            s1 += v0 + v1; s2 += v0 * v0 + v1 * v1;
        }
    }
    #pragma unroll
    for (int d = 32; d > 0; d >>= 1) { s1 += __shfl_xor(s1, d); s2 += __shfl_xor(s2, d); }
    float mu = s1 / (float)HID;
    float var = s2 / (float)HID - mu * mu;
    float rstd = rsqrtf(var + 1e-5f);
    #pragma unroll
    for (int h = 0; h < NH; ++h) {
        int cb = h * CH + lane * 8;
        f32x4 g0 = *(const f32x4*)&gammav[layer * HID + cb];
        f32x4 g1 = *(const f32x4*)&gammav[layer * HID + cb + 4];
        f32x4 e0 = *(const f32x4*)&betav[layer * HID + cb];
        f32x4 e1 = *(const f32x4*)&betav[layer * HID + cb + 4];
        u16x4 o0, o1;
        #pragma unroll
        for (int j = 0; j < 4; ++j) {
            float y0 = (val[h][j] - mu) * rstd * g0[j] + e0[j];
            float y1 = (val[h][4 + j] - mu) * rstd * g1[j] + e1[j];
            o0[j] = f2bf(fmaxf(y0, 0.f));
            o1[j] = f2bf(fmaxf(y1, 0.f));
        }
        *(u16x4*)&hout[(size_t)n * HID + cb]     = o0;
        *(u16x4*)&hout[(size_t)n * HID + cb + 4] = o1;
    }
}

// ---------- subgraph -> atom aggregation via CSR gather (no atomics) ----------
__global__ __launch_bounds__(256) void k_agg(const ushortT* __restrict__ hbf,
                                             const int* __restrict__ rs2,
                                             const int* __restrict__ ids2,
                                             float* __restrict__ agg) {
    int a = blockIdx.x;
    int beg = rs2[a], end = rs2[a + 1];
    int col = threadIdx.x * 8;
    float acc[8] = {0,0,0,0,0,0,0,0};
    for (int pos = beg; pos < end; ++pos) {
        int i = ids2[pos];
        const u16x4* ptr = (const u16x4*)(hbf + (size_t)i * HID + col);
        u16x4 h0 = ptr[0], h1 = ptr[1];
        #pragma unroll
        for (int t = 0; t < 4; ++t) { acc[t] += bf2f(h0[t]); acc[4 + t] += bf2f(h1[t]); }
    }
    int cnt = end - beg;
    float inv = 1.f / (float)(cnt > 1 ? cnt : 1);
    f32x4 o0, o1;
    #pragma unroll
    for (int t = 0; t < 4; ++t) { o0[t] = acc[t] * inv; o1[t] = acc[4 + t] * inv; }
    float* dst = agg + (size_t)a * HID + col;
    *(f32x4*)dst = o0;
    *(f32x4*)(dst + 4) = o1;
}

__global__ void k_branges(const int* __restrict__ batch, int* __restrict__ bstart,
                          int* __restrict__ bend) {
    int a = blockIdx.x * 256 + threadIdx.x;
    if (a < N_ATOMS) {
        int b = batch[a];
        atomicMin(&bstart[b], a);
        atomicMax(&bend[b], a + 1);
    }
}

// ---------- per-molecule mean of atom aggregates ----------
__global__ __launch_bounds__(128) void k_pool(const float* __restrict__ agg,
                                              const int* __restrict__ bstart,
                                              const int* __restrict__ bend,
                                              float* __restrict__ pa) {
    int b = blockIdx.x;
    int col = blockIdx.y * 128 + threadIdx.x;
    int s = bstart[b], e = bend[b];
    float v = 0.f;
    for (int a = s; a < e; ++a) v += agg[(size_t)a * HID + col];
    int g = e - s;
    pa[b * HID + col] = (g > 0) ? v / (float)g : 0.f;
}

// ---------- final projection, split-K pass 1: part[kc][b][col] ----------
__global__ __launch_bounds__(256) void k_fpart(const float* __restrict__ pa,
                                               const float* __restrict__ Wf,
                                               float* __restrict__ part) {
    int kc = blockIdx.x;            // 16 k-chunks of 128
    int col = blockIdx.y * 256 + threadIdx.x;
    int k0 = kc * 128;
    __shared__ float pl[NBATCH][128];
    for (int i = threadIdx.x; i < NBATCH * 128; i += 256) {
        int b = i >> 7, k = i & 127;
        pl[b][k] = pa[b * HID + k0 + k];
    }
    __syncthreads();
    float acc[NBATCH];
    #pragma unroll
    for (int b = 0; b < NBATCH; ++b) acc[b] = 0.f;
    for (int kk = 0; kk < 128; kk += 4) {
        f32x4 w;
        #pragma unroll
        for (int u = 0; u < 4; ++u) w[u] = Wf[(size_t)(k0 + kk + u) * HID + col];
        #pragma unroll
        for (int b = 0; b < NBATCH; ++b) {
            f32x4 pv = *(const f32x4*)&pl[b][kk];
            acc[b] += pv[0] * w[0] + pv[1] * w[1] + pv[2] * w[2] + pv[3] * w[3];
        }
    }
    #pragma unroll
    for (int b = 0; b < NBATCH; ++b)
        part[((size_t)kc * NBATCH + b) * HID + col] = acc[b];
}

// ---------- final projection, pass 2: deterministic reduce + bias ----------
__global__ __launch_bounds__(256) void k_fred(const float* __restrict__ part,
                                              const float* __restrict__ bfv,
                                              const int* __restrict__ bstart,
                                              const int* __restrict__ bend,
                                              float* __restrict__ out) {
    int b = blockIdx.x;
    int col = blockIdx.y * 256 + threadIdx.x;
    float s = 0.f;
    #pragma unroll
    for (int kc = 0; kc < 16; ++kc)
        s += part[((size_t)kc * NBATCH + b) * HID + col];
    int g = bend[b] - bstart[b];
    out[b * HID + col] = (g > 0) ? s + bfv[col] : 0.f;
}

extern "C" void kernel_launch(void* const* d_in, const int* in_sizes, int n_in,
                              void* d_out, int out_size, void* d_ws, size_t ws_size,
                              hipStream_t stream) {
    const float* x         = (const float*)d_in[0];
    const float* ea        = (const float*)d_in[1];
    const float* Wn        = (const float*)d_in[2];
    const float* bn        = (const float*)d_in[3];
    const float* We        = (const float*)d_in[4];
    const float* be        = (const float*)d_in[5];
    const float* W0        = (const float*)d_in[6];
    const float* Ws        = (const float*)d_in[7];
    const float* att_src   = (const float*)d_in[8];
    const float* att_dst   = (const float*)d_in[9];
    const float* att_edge  = (const float*)d_in[10];
    const float* W_edge    = (const float*)d_in[11];
    const float* conv_bias = (const float*)d_in[12];
    const float* gammav    = (const float*)d_in[13];
    const float* betav     = (const float*)d_in[14];
    const float* Wf        = (const float*)d_in[15];
    const float* bfv       = (const float*)d_in[16];
    const int* sni         = (const int*)d_in[17];
    const int* sei         = (const int*)d_in[18];
    const int* sind        = (const int*)d_in[19];
    const int* batch       = (const int*)d_in[20];
    float* out = (float*)d_out;

    char* p = (char*)d_ws;
    auto carve = [&](size_t bytes) -> char* {
        char* r = p; p += (bytes + 255) & ~(size_t)255; return r;
    };
    // total ~229 MB
    ushortT* Wt0   = (ushortT*)carve((size_t)HID * EMB * 2);
    ushortT* Wt1   = (ushortT*)carve((size_t)HID * HID * 2);
    ushortT* Wt2   = (ushortT*)carve((size_t)HID * HID * 2);
    ushortT* xpb   = (ushortT*)carve((size_t)AP * EMB * 2);      // 12.3 MB (padded)
    ushortT* xha   = (ushortT*)carve((size_t)AP * HID * 2);      // 24.6 MB
    ushortT* hbf   = (ushortT*)carve((size_t)MP * HID * 2);      // 82.3 MB
    ushortT* xhb   = (ushortT*)carve((size_t)MP * HID * 2);      // 82.3 MB
    float*   ssrc  = (float*)carve((size_t)MP * NH * 4);
    float*   sdstb = (float*)carve((size_t)MP * NH * 4);
    float*   ssrca = (float*)carve((size_t)AP * NH * 4);
    float*   sdsta = (float*)carve((size_t)AP * NH * 4);
    float*   pq    = (float*)carve(NL * NH * 2 * 4);
    float*   meana = (float*)carve(256);
    float*   pqpart= (float*)carve((size_t)16 * 12 * 2 * 4);
    float*   mpart = (float*)carve(64 * 4);
    int*     cntdeg= (int*)carve((size_t)NSUB * 4);
    int*     rs    = (int*)carve((size_t)(NSUB + 1) * 4);
    int*     cursor= (int*)carve((size_t)NSUB * 4);
    int*     eids  = (int*)carve((size_t)ETOT * 4);
    int*     esrcS = (int*)carve((size_t)ETOT * 4);
    int*     esrcA = (int*)carve((size_t)ETOT * 4);
    float*   eaf   = (float*)carve((size_t)ETOT * 4);
    int*     cnt2  = (int*)carve((size_t)N_ATOMS * 4);
    int*     rs2   = (int*)carve((size_t)(N_ATOMS + 1) * 4);
    int*     cur2  = (int*)carve((size_t)N_ATOMS * 4);
    int*     ids2  = (int*)carve((size_t)NSUB * 4);
    int*     bstart= (int*)carve(NBATCH * 4);
    int*     bend  = (int*)carve(NBATCH * 4);
    float*   pa    = (float*)carve((size_t)NBATCH * HID * 4);
    float*   part  = (float*)carve((size_t)16 * NBATCH * HID * 4);  // 2 MB
    float*   agg   = (float*)xhb;  // overlay: xhb dead after last k_attn

    // pad rows + per-call zero-init
    hipMemsetAsync(hbf + (size_t)NSUB * HID, 0, (size_t)(MP - NSUB) * HID * 2, stream);
    hipMemsetAsync(xpb + (size_t)N_ATOMS * EMB, 0, (size_t)(AP - N_ATOMS) * EMB * 2, stream);
    hipMemsetAsync(cntdeg, 0, (size_t)NSUB * 4, stream);
    hipMemsetAsync(cursor, 0, (size_t)NSUB * 4, stream);
    hipMemsetAsync(cnt2, 0, (size_t)N_ATOMS * 4, stream);
    hipMemsetAsync(cur2, 0, (size_t)N_ATOMS * 4, stream);
    hipMemsetAsync(bstart, 0x7f, NBATCH * 4, stream);
    hipMemsetAsync(bend, 0, NBATCH * 4, stream);

    dim3 tb(32, 8);
    k_cast_transpose<<<dim3(HID / 32, EMB / 32), tb, 0, stream>>>(W0, Wt0, EMB, HID);
    k_cast_transpose<<<dim3(HID / 32, HID / 32), tb, 0, stream>>>(Ws, Wt1, HID, HID);
    k_cast_transpose<<<dim3(HID / 32, HID / 32), tb, 0, stream>>>(Ws + (size_t)HID * HID, Wt2, HID, HID);

    k_node_proj<<<N_ATOMS / NPB, 256, 0, stream>>>(x, Wn, bn, xpb);
    k_mean_part<<<64, 256, 0, stream>>>(ea, mpart);
    k_pq_part<<<dim3(NL * NH, 16), 256, 0, stream>>>(We, be, W_edge, att_edge, pqpart);
    k_pq_red<<<1, 64, 0, stream>>>(pqpart, mpart, pq, meana);

    const int* dsti = sei + NEDGE;
    k_eprep<<<(ETOT + 255) / 256, 256, 0, stream>>>(sei, sni, ea, meana, esrcS, esrcA, eaf);
    k_count<<<(ETOT + 255) / 256, 256, 0, stream>>>(dsti, cntdeg);
    k_scan<<<1, 1024, 0, stream>>>(cntdeg, rs, NSUB);
    k_fill<<<(ETOT + 255) / 256, 256, 0, stream>>>(dsti, rs, cursor, eids);
    k_count_ind<<<(NSUB + 255) / 256, 256, 0, stream>>>(sind, cnt2);
    k_scan<<<1, 1024, 0, stream>>>(cnt2, rs2, N_ATOMS);
    k_fill_ind<<<(NSUB + 255) / 256, 256, 0, stream>>>(sind, rs2, cur2, ids2);
    k_branges<<<(N_ATOMS + 255) / 256, 256, 0, stream>>>(batch, bstart, bend);

    // ---- layer 0 at atom level: xha = xpb @ W0, sdots at atom level; attn
    //      gathers straight from xha via per-edge atom indices (no xhb copy) ----
    k_gemm<<<dim3(AP / 128, HID / 128), 256, 0, stream>>>(xpb, Wt0, xha, EMB);
    k_sdots<<<N_ATOMS, 256, 0, stream>>>(xha, att_src, att_dst, ssrca, sdsta, 0);
    k_attn<<<NSUB / 4, 256, 0, stream>>>(xha, ssrca, sdsta, rs, eids, esrcA, eaf, pq,
                                         conv_bias, gammav, betav, hbf, 0, sni);

    // ---- layers 1..2 on subgraph domain ----
    for (int l = 1; l < NL; ++l) {
        const ushortT* Wt = (l == 1) ? Wt1 : Wt2;
        k_gemm<<<dim3(MP / 128, HID / 128), 256, 0, stream>>>(hbf, Wt, xhb, HID);
        k_sdots<<<NSUB, 256, 0, stream>>>(xhb, att_src, att_dst, ssrc, sdstb, l);
        k_attn<<<NSUB / 4, 256, 0, stream>>>(xhb, ssrc, sdstb, rs, eids, esrcS, eaf, pq,
                                             conv_bias, gammav, betav, hbf, l, (const int*)nullptr);
    }

    k_agg<<<N_ATOMS, 256, 0, stream>>>(hbf, rs2, ids2, agg);
    k_pool<<<dim3(NBATCH, HID / 128), 128, 0, stream>>>(agg, bstart, bend, pa);
    k_fpart<<<dim3(16, HID / 256), 256, 0, stream>>>(pa, Wf, part);
    k_fred<<<dim3(NBATCH, HID / 256), 256, 0, stream>>>(part, bfv, bstart, bend, out);
}

// Round 14
// 957.120 us; speedup vs baseline: 1.0418x; 1.0418x over previous
//
#include <hip/hip_runtime.h>

typedef unsigned short ushortT;
typedef __attribute__((ext_vector_type(4))) float f32x4;
typedef __attribute__((ext_vector_type(8))) short bf16x8;
typedef __attribute__((ext_vector_type(4))) unsigned int u32x4;
typedef __attribute__((ext_vector_type(4))) unsigned short u16x4;

#define N_ATOMS 6000
#define NSUB    20000
#define NEDGE   60000
#define NBATCH  16
#define INDIM   78
#define EMB     1024
#define HID     2048
#define NH      4
#define CH      512
#define NL      3
#define MP      20096          // NSUB padded to multiple of 128
#define AP      6016           // N_ATOMS padded to multiple of 128
#define ETOT    (NEDGE + NSUB) // edges + self loops
#define NPB     8              // atoms per block in k_node_proj

#define GLOAD_LDS16(gp, lp) \
    __builtin_amdgcn_global_load_lds((const __attribute__((address_space(1))) void*)(gp), \
                                     (__attribute__((address_space(3))) void*)(lp), 16, 0, 0)

__device__ __forceinline__ ushortT f2bf(float x) {
    union { float f; unsigned u; } v; v.f = x;
    unsigned r = v.u + 0x7fffu + ((v.u >> 16) & 1u);   // RNE
    return (ushortT)(r >> 16);
}
__device__ __forceinline__ float bf2f(ushortT h) {
    union { unsigned u; float f; } v; v.u = ((unsigned)h) << 16; return v.f;
}

// ---------- weight cast + transpose, all three matrices in one launch ----------
// All three weight matrices are [K x HID] row-major (K = EMB or HID).
__global__ void k_cast3(const float* __restrict__ W0, const float* __restrict__ Ws,
                        ushortT* __restrict__ Wt0, ushortT* __restrict__ Wt1,
                        ushortT* __restrict__ Wt2) {
    __shared__ float tile[32][33];
    int z = blockIdx.z;
    const float* W = (z == 0) ? W0 : (z == 1 ? Ws : Ws + (size_t)HID * HID);
    ushortT* Wt = (z == 0) ? Wt0 : (z == 1 ? Wt1 : Wt2);
    int K = (z == 0) ? EMB : HID;
    int n0 = blockIdx.x * 32, k0 = blockIdx.y * 32;
    if (k0 >= K) return;
    int tx = threadIdx.x, ty = threadIdx.y; // 32 x 8
    for (int i = 0; i < 32; i += 8)
        tile[ty + i][tx] = W[(size_t)(k0 + ty + i) * HID + n0 + tx];
    __syncthreads();
    for (int i = 0; i < 32; i += 8)
        Wt[(size_t)(n0 + ty + i) * K + k0 + tx] = f2bf(tile[tx][ty + i]);
}

// ---------- node projection: xpb = bf16(x @ Wn + bn), 8 atoms/block ----------
__global__ __launch_bounds__(256) void k_node_proj(const float* __restrict__ x,
                                                   const float* __restrict__ Wn,
                                                   const float* __restrict__ bn,
                                                   ushortT* __restrict__ xpb) {
    int n0 = blockIdx.x * NPB;
    __shared__ float xr[NPB][INDIM];
    int tid = threadIdx.x;
    for (int i = tid; i < NPB * INDIM; i += 256)
        xr[i / INDIM][i % INDIM] = x[(size_t)(n0 + i / INDIM) * INDIM + (i % INDIM)];
    __syncthreads();
    for (int j = tid; j < EMB; j += 256) {
        float acc[NPB];
        float b = bn[j];
        #pragma unroll
        for (int a = 0; a < NPB; ++a) acc[a] = b;
        #pragma unroll 6
        for (int k = 0; k < INDIM; ++k) {
            float wv = Wn[(size_t)k * EMB + j];
            #pragma unroll
            for (int a = 0; a < NPB; ++a) acc[a] += xr[a][k] * wv;
        }
        #pragma unroll
        for (int a = 0; a < NPB; ++a)
            xpb[(size_t)(n0 + a) * EMB + j] = f2bf(acc[a]);
    }
}

// ---------- mean of edge_attr, pass 1: 64 deterministic partials ----------
__global__ void k_mean_part(const float* __restrict__ ea, float* __restrict__ mpart) {
    __shared__ float red[256];
    int b = blockIdx.x;
    float s = 0;
    for (int i = b * 256 + threadIdx.x; i < NEDGE; i += 64 * 256) s += ea[i];
    red[threadIdx.x] = s; __syncthreads();
    for (int d = 128; d > 0; d >>= 1) {
        if (threadIdx.x < d) red[threadIdx.x] += red[threadIdx.x + d];
        __syncthreads();
    }
    if (threadIdx.x == 0) mpart[b] = red[0];
}

// ---------- edge-attention scalars p,q: split-K partials (12 x 16 blocks) ----------
__global__ __launch_bounds__(256) void k_pq_part(const float* __restrict__ We,
                                                 const float* __restrict__ be,
                                                 const float* __restrict__ W_edge,
                                                 const float* __restrict__ att_edge,
                                                 float* __restrict__ part) {
    int l = blockIdx.x >> 2, h = blockIdx.x & 3;
    int k0 = blockIdx.y * 64;
    const float* Wl = W_edge + (size_t)l * EMB * HID + h * CH;
    const float* ae = att_edge + ((size_t)l * NH + h) * CH;
    int tid = threadIdx.x;
    float aP0 = 0, aP1 = 0, aQ0 = 0, aQ1 = 0;
    #pragma unroll 4
    for (int k = k0; k < k0 + 64; ++k) {
        float wek = We[k], bek = be[k];
        float w0 = Wl[(size_t)k * HID + tid];
        float w1 = Wl[(size_t)k * HID + tid + 256];
        aP0 += wek * w0; aP1 += wek * w1;
        aQ0 += bek * w0; aQ1 += bek * w1;
    }
    float p = aP0 * ae[tid] + aP1 * ae[tid + 256];
    float q = aQ0 * ae[tid] + aQ1 * ae[tid + 256];
    __shared__ float rp[256], rq[256];
    rp[tid] = p; rq[tid] = q; __syncthreads();
    for (int d = 128; d > 0; d >>= 1) {
        if (tid < d) { rp[tid] += rp[tid + d]; rq[tid] += rq[tid + d]; }
        __syncthreads();
    }
    if (tid == 0) {
        part[((size_t)blockIdx.y * 12 + blockIdx.x) * 2]     = rp[0];
        part[((size_t)blockIdx.y * 12 + blockIdx.x) * 2 + 1] = rq[0];
    }
}

// ---------- pq + mean final reduce (fixed order, deterministic) ----------
__global__ void k_pq_red(const float* __restrict__ part, const float* __restrict__ mpart,
                         float* __restrict__ pq, float* __restrict__ meana) {
    int t = threadIdx.x;
    if (t < 24) {
        float s = 0;
        for (int kc = 0; kc < 16; ++kc) s += part[((size_t)kc * 12 + (t >> 1)) * 2 + (t & 1)];
        pq[t] = s;
    }
    if (t == 32) {
        float s = 0;
        for (int i = 0; i < 64; ++i) s += mpart[i];
        meana[0] = s / (float)NEDGE;
    }
}

// ---------- merged counters: edge-degree + subgraph-indicator + batch ranges ----------
__global__ void k_counts(const int* __restrict__ dsti, const int* __restrict__ sind,
                         const int* __restrict__ batch,
                         int* __restrict__ cntdeg, int* __restrict__ cnt2,
                         int* __restrict__ bstart, int* __restrict__ bend) {
    int t = blockIdx.x * 256 + threadIdx.x;
    if (t < ETOT) {
        int d = (t < NEDGE) ? dsti[t] : (t - NEDGE);
        atomicAdd(&cntdeg[d], 1);
    } else if (t < ETOT + NSUB) {
        atomicAdd(&cnt2[sind[t - ETOT]], 1);
    } else if (t < ETOT + NSUB + N_ATOMS) {
        int a = t - ETOT - NSUB;
        int b = batch[a];
        atomicMin(&bstart[b], a);
        atomicMax(&bend[b], a + 1);
    }
}

// exclusive scan over n counts -> rs[0..n], single 1024-thread block
__global__ void k_scan(const int* __restrict__ cnt, int* __restrict__ rs, int n) {
    __shared__ int part[1024];
    int tid = threadIdx.x;
    const int per = (n + 1023) / 1024;
    int base = tid * per;
    int s = 0;
    for (int i = 0; i < per; ++i) { int idx = base + i; if (idx < n) s += cnt[idx]; }
    part[tid] = s;
    __syncthreads();
    for (int d = 1; d < 1024; d <<= 1) {
        int v = (tid >= d) ? part[tid - d] : 0;
        __syncthreads();
        part[tid] += v;
        __syncthreads();
    }
    int off = part[tid] - s; // exclusive
    for (int i = 0; i < per; ++i) {
        int idx = base + i;
        if (idx < n) { rs[idx] = off; off += cnt[idx]; }
    }
    if (tid == 1023) rs[n] = part[1023];
}

// ---------- merged fills: CSR edge fill (pos-ordered src/attr, inline eprep)
//            + subgraph-indicator fill ----------
__global__ void k_fills(const int* __restrict__ dsti, const int* __restrict__ srci,
                        const int* __restrict__ sni, const float* __restrict__ ea,
                        const float* __restrict__ meana, const int* __restrict__ sind,
                        const int* __restrict__ rs, const int* __restrict__ rs2,
                        int* __restrict__ cursor, int* __restrict__ cur2,
                        int* __restrict__ esrcPS, int* __restrict__ esrcPA,
                        float* __restrict__ eafP, int* __restrict__ ids2) {
    int t = blockIdx.x * 256 + threadIdx.x;
    if (t < ETOT) {
        int d, s; float a;
        if (t < NEDGE) { d = dsti[t]; s = srci[t]; a = ea[t]; }
        else           { d = t - NEDGE; s = d;     a = meana[0]; }
        int pos = rs[d] + atomicAdd(&cursor[d], 1);
        esrcPS[pos] = s;
        esrcPA[pos] = sni[s];
        eafP[pos] = a;
    } else if (t < ETOT + NSUB) {
        int i = t - ETOT;
        int aT = sind[i];
        int pos = rs2[aT] + atomicAdd(&cur2[aT], 1);
        ids2[pos] = i;
    }
}

// ---------- bf16 MFMA GEMM (proven 869 TF): gload_lds + involution swizzle ----------
__global__ __launch_bounds__(256) void k_gemm(const ushortT* __restrict__ A,
                                              const ushortT* __restrict__ Bt,
                                              ushortT* __restrict__ Cb, int K) {
    __shared__ alignas(16) ushortT As[128 * 64];   // 16 KB
    __shared__ alignas(16) ushortT Bs[128 * 64];   // 16 KB
    const int tid = threadIdx.x;
    const int nx = (int)gridDim.x;                 // bm tiles
    const int ny = (int)gridDim.y;                 // 16  (bn tiles)
    int o = (int)blockIdx.y * nx + (int)blockIdx.x;  // dispatch order (bx fast)
    int cpx = (nx * ny) >> 3;                        // blocks per XCD
    int s = (o & 7) * cpx + (o >> 3);                // sequential id within XCD span
    const int bm = s / ny, bn = s % ny;              // bn fast -> A-panel reuse
    const int wave = tid >> 6, lane = tid & 63;
    const int wr = wave >> 1, wc = wave & 1;
    f32x4 acc[4][4] = {};
    const int frow = lane & 15;          // fragment row within 16
    const int cb0  = lane >> 4;          // k col-block 0..3 (8 elems each)
    const ushortT* Ab = A + (size_t)bm * 128 * K;
    const ushortT* Bb = Bt + (size_t)bn * 128 * K;
    const int srow = (lane >> 3);                        // 0..7 within chunk
    const int sswz = (((lane & 7) ^ srow) << 3);         // swizzled elem col
    for (int k0 = 0; k0 < K; k0 += 64) {
        #pragma unroll
        for (int i = 0; i < 4; ++i) {
            int c = wave * 4 + i;                        // chunk 0..15
            int r = c * 8 + srow;                        // tile row 0..127
            GLOAD_LDS16(Ab + (size_t)r * K + k0 + sswz, As + c * 512 + lane * 8);
            GLOAD_LDS16(Bb + (size_t)r * K + k0 + sswz, Bs + c * 512 + lane * 8);
        }
        __syncthreads();
        #pragma unroll
        for (int kk = 0; kk < 64; kk += 32) {
            bf16x8 af[4], bfr[4];
            #pragma unroll
            for (int m = 0; m < 4; ++m) {
                int row = wr * 64 + m * 16 + frow;
                int cb = (kk >> 3) + cb0;
                af[m] = *(const bf16x8*)&As[row * 64 + ((cb ^ (frow & 7)) << 3)];
            }
            #pragma unroll
            for (int n = 0; n < 4; ++n) {
                int row = wc * 64 + n * 16 + frow;
                int cb = (kk >> 3) + cb0;
                bfr[n] = *(const bf16x8*)&Bs[row * 64 + ((cb ^ (frow & 7)) << 3)];
            }
            #pragma unroll
            for (int m = 0; m < 4; ++m)
                #pragma unroll
                for (int n = 0; n < 4; ++n)
                    acc[m][n] = __builtin_amdgcn_mfma_f32_16x16x32_bf16(af[m], bfr[n], acc[m][n], 0, 0, 0);
        }
        __syncthreads();
    }
    const int cr = (lane >> 4) * 4;
    const int cc = lane & 15;
    #pragma unroll
    for (int m = 0; m < 4; ++m)
        #pragma unroll
        for (int n = 0; n < 4; ++n)
            #pragma unroll
            for (int r = 0; r < 4; ++r) {
                size_t row = (size_t)bm * 128 + wr * 64 + m * 16 + cr + r;
                int col = bn * 128 + wc * 64 + n * 16 + cc;
                Cb[row * HID + col] = f2bf(acc[m][n][r]);
            }
}

// ---------- per-(node,head) attention dot scalars (bf16 xh) ----------
__global__ __launch_bounds__(256) void k_sdots(const ushortT* __restrict__ xh,
                                               const float* __restrict__ att_src,
                                               const float* __restrict__ att_dst,
                                               float* __restrict__ ssrc,
                                               float* __restrict__ sdst, int layer) {
    int n = blockIdx.x;
    int h = threadIdx.x >> 6, lane = threadIdx.x & 63;
    const ushortT* row = xh + (size_t)n * HID + h * CH + lane * 8;
    const float* as = att_src + ((size_t)layer * NH + h) * CH + lane * 8;
    const float* ad = att_dst + ((size_t)layer * NH + h) * CH + lane * 8;
    u16x4 v0 = *(const u16x4*)row, v1 = *(const u16x4*)(row + 4);
    f32x4 a0 = *(const f32x4*)as, a1 = *(const f32x4*)(as + 4);
    f32x4 d0 = *(const f32x4*)ad, d1 = *(const f32x4*)(ad + 4);
    float ps = 0.f, pd = 0.f;
    #pragma unroll
    for (int t = 0; t < 4; ++t) {
        float f0 = bf2f(v0[t]), f1 = bf2f(v1[t]);
        ps += f0 * a0[t] + f1 * a1[t];
        pd += f0 * d0[t] + f1 * d1[t];
    }
    #pragma unroll
    for (int d = 32; d > 0; d >>= 1) { ps += __shfl_down(ps, d); pd += __shfl_down(pd, d); }
    if (lane == 0) { ssrc[n * NH + h] = ps; sdst[n * NH + h] = pd; }
}

// ---------- fused attention: one wave per dst, CSR-ordered edge data ----------
// esrcP/eafP are indexed by CSR position (no eids indirection). nmap: layer-0
// dst->atom remap for sdst.
__global__ __launch_bounds__(256) void k_attn(const ushortT* __restrict__ xh,
                                              const float* __restrict__ ssrc,
                                              const float* __restrict__ sdst,
                                              const int* __restrict__ rs,
                                              const int* __restrict__ esrcP,
                                              const float* __restrict__ eafP,
                                              const float* __restrict__ pq,
                                              const float* __restrict__ conv_bias,
                                              const float* __restrict__ gammav,
                                              const float* __restrict__ betav,
                                              ushortT* __restrict__ hout, int layer,
                                              const int* __restrict__ nmap) {
    int wv = threadIdx.x >> 6, lane = threadIdx.x & 63;
    int n = blockIdx.x * 4 + wv;       // NSUB = 5000 blocks * 4 waves, exact
    int nn = nmap ? nmap[n] : n;
    int beg = rs[n], end = rs[n + 1];
    f32x4 pq01 = *(const f32x4*)&pq[layer * 8];
    f32x4 pq23 = *(const f32x4*)&pq[layer * 8 + 4];
    float px[NH] = {pq01[0], pq01[2], pq23[0], pq23[2]};
    float qx[NH] = {pq01[1], pq01[3], pq23[1], pq23[3]};
    f32x4 sdv = *(const f32x4*)&sdst[nn * NH];
    float m[NH], z[NH];
    #pragma unroll
    for (int h = 0; h < NH; ++h) { m[h] = -INFINITY; z[h] = 0.f; }
    float facc[NH][8] = {};
    for (int pos = beg; pos < end; ++pos) {
        int s = esrcP[pos];
        float a = eafP[pos];
        f32x4 ssv = *(const f32x4*)&ssrc[s * NH];
        const ushortT* xr = xh + (size_t)s * HID + lane * 8;
        #pragma unroll
        for (int h = 0; h < NH; ++h) {
            float logit = ssv[h] + sdv[h] + a * px[h] + qx[h];
            logit = (logit > 0.f) ? logit : 0.2f * logit;
            float mn = fmaxf(m[h], logit);
            float scale = expf(m[h] - mn);   // 0 when m == -inf
            float w = expf(logit - mn);
            z[h] = z[h] * scale + w;
            bf16x8 u = *(const bf16x8*)(xr + h * CH);
            #pragma unroll
            for (int j = 0; j < 8; ++j)
                facc[h][j] = facc[h][j] * scale + w * bf2f((ushortT)u[j]);
            m[h] = mn;
        }
    }
    // bias + LN stats over the wave's 2048 channels (32 per lane)
    float val[NH][8];
    float s1 = 0.f, s2 = 0.f;
    #pragma unroll
    for (int h = 0; h < NH; ++h) {
        float inv = 1.f / (z[h] + 1e-16f);
        int cb = h * CH + lane * 8;
        f32x4 b0 = *(const f32x4*)&conv_bias[layer * HID + cb];
        f32x4 b1 = *(const f32x4*)&conv_bias[layer * HID + cb + 4];
        #pragma unroll
        for (int j = 0; j < 4; ++j) {
            float v0 = facc[h][j] * inv + b0[j];
            float v1 = facc[h][4 + j] * inv + b1[j];
            val[h][j] = v0; val[h][4 + j] = v1;
            s1 += v0 + v1; s2 += v0 * v0 + v1 * v1;
        }
    }
    #pragma unroll
    for (int d = 32; d > 0; d >>= 1) { s1 += __shfl_xor(s1, d); s2 += __shfl_xor(s2, d); }
    float mu = s1 / (float)HID;
    float var = s2 / (float)HID - mu * mu;
    float rstd = rsqrtf(var + 1e-5f);
    #pragma unroll
    for (int h = 0; h < NH; ++h) {
        int cb = h * CH + lane * 8;
        f32x4 g0 = *(const f32x4*)&gammav[layer * HID + cb];
        f32x4 g1 = *(const f32x4*)&gammav[layer * HID + cb + 4];
        f32x4 e0 = *(const f32x4*)&betav[layer * HID + cb];
        f32x4 e1 = *(const f32x4*)&betav[layer * HID + cb + 4];
        u16x4 o0, o1;
        #pragma unroll
        for (int j = 0; j < 4; ++j) {
            float y0 = (val[h][j] - mu) * rstd * g0[j] + e0[j];
            float y1 = (val[h][4 + j] - mu) * rstd * g1[j] + e1[j];
            o0[j] = f2bf(fmaxf(y0, 0.f));
            o1[j] = f2bf(fmaxf(y1, 0.f));
        }
        *(u16x4*)&hout[(size_t)n * HID + cb]     = o0;
        *(u16x4*)&hout[(size_t)n * HID + cb + 4] = o1;
    }
}

// ---------- subgraph -> atom aggregation via CSR gather (no atomics) ----------
__global__ __launch_bounds__(256) void k_agg(const ushortT* __restrict__ hbf,
                                             const int* __restrict__ rs2,
                                             const int* __restrict__ ids2,
                                             float* __restrict__ agg) {
    int a = blockIdx.x;
    int beg = rs2[a], end = rs2[a + 1];
    int col = threadIdx.x * 8;
    float acc[8] = {0,0,0,0,0,0,0,0};
    for (int pos = beg; pos < end; ++pos) {
        int i = ids2[pos];
        const u16x4* ptr = (const u16x4*)(hbf + (size_t)i * HID + col);
        u16x4 h0 = ptr[0], h1 = ptr[1];
        #pragma unroll
        for (int t = 0; t < 4; ++t) { acc[t] += bf2f(h0[t]); acc[4 + t] += bf2f(h1[t]); }
    }
    int cnt = end - beg;
    float inv = 1.f / (float)(cnt > 1 ? cnt : 1);
    f32x4 o0, o1;
    #pragma unroll
    for (int t = 0; t < 4; ++t) { o0[t] = acc[t] * inv; o1[t] = acc[4 + t] * inv; }
    float* dst = agg + (size_t)a * HID + col;
    *(f32x4*)dst = o0;
    *(f32x4*)(dst + 4) = o1;
}

// ---------- per-molecule mean of atom aggregates ----------
__global__ __launch_bounds__(128) void k_pool(const float* __restrict__ agg,
                                              const int* __restrict__ bstart,
                                              const int* __restrict__ bend,
                                              float* __restrict__ pa) {
    int b = blockIdx.x;
    int col = blockIdx.y * 128 + threadIdx.x;
    int s = bstart[b], e = bend[b];
    float v = 0.f;
    for (int a = s; a < e; ++a) v += agg[(size_t)a * HID + col];
    int g = e - s;
    pa[b * HID + col] = (g > 0) ? v / (float)g : 0.f;
}

// ---------- final projection, split-K pass 1: part[kc][b][col] ----------
__global__ __launch_bounds__(256) void k_fpart(const float* __restrict__ pa,
                                               const float* __restrict__ Wf,
                                               float* __restrict__ part) {
    int kc = blockIdx.x;            // 16 k-chunks of 128
    int col = blockIdx.y * 256 + threadIdx.x;
    int k0 = kc * 128;
    __shared__ float pl[NBATCH][128];
    for (int i = threadIdx.x; i < NBATCH * 128; i += 256) {
        int b = i >> 7, k = i & 127;
        pl[b][k] = pa[b * HID + k0 + k];
    }
    __syncthreads();
    float acc[NBATCH];
    #pragma unroll
    for (int b = 0; b < NBATCH; ++b) acc[b] = 0.f;
    for (int kk = 0; kk < 128; kk += 4) {
        f32x4 w;
        #pragma unroll
        for (int u = 0; u < 4; ++u) w[u] = Wf[(size_t)(k0 + kk + u) * HID + col];
        #pragma unroll
        for (int b = 0; b < NBATCH; ++b) {
            f32x4 pv = *(const f32x4*)&pl[b][kk];
            acc[b] += pv[0] * w[0] + pv[1] * w[1] + pv[2] * w[2] + pv[3] * w[3];
        }
    }
    #pragma unroll
    for (int b = 0; b < NBATCH; ++b)
        part[((size_t)kc * NBATCH + b) * HID + col] = acc[b];
}

// ---------- final projection, pass 2: deterministic reduce + bias ----------
__global__ __launch_bounds__(256) void k_fred(const float* __restrict__ part,
                                              const float* __restrict__ bfv,
                                              const int* __restrict__ bstart,
                                              const int* __restrict__ bend,
                                              float* __restrict__ out) {
    int b = blockIdx.x;
    int col = blockIdx.y * 256 + threadIdx.x;
    float s = 0.f;
    #pragma unroll
    for (int kc = 0; kc < 16; ++kc)
        s += part[((size_t)kc * NBATCH + b) * HID + col];
    int g = bend[b] - bstart[b];
    out[b * HID + col] = (g > 0) ? s + bfv[col] : 0.f;
}

extern "C" void kernel_launch(void* const* d_in, const int* in_sizes, int n_in,
                              void* d_out, int out_size, void* d_ws, size_t ws_size,
                              hipStream_t stream) {
    const float* x         = (const float*)d_in[0];
    const float* ea        = (const float*)d_in[1];
    const float* Wn        = (const float*)d_in[2];
    const float* bn        = (const float*)d_in[3];
    const float* We        = (const float*)d_in[4];
    const float* be        = (const float*)d_in[5];
    const float* W0        = (const float*)d_in[6];
    const float* Ws        = (const float*)d_in[7];
    const float* att_src   = (const float*)d_in[8];
    const float* att_dst   = (const float*)d_in[9];
    const float* att_edge  = (const float*)d_in[10];
    const float* W_edge    = (const float*)d_in[11];
    const float* conv_bias = (const float*)d_in[12];
    const float* gammav    = (const float*)d_in[13];
    const float* betav     = (const float*)d_in[14];
    const float* Wf        = (const float*)d_in[15];
    const float* bfv       = (const float*)d_in[16];
    const int* sni         = (const int*)d_in[17];
    const int* sei         = (const int*)d_in[18];
    const int* sind        = (const int*)d_in[19];
    const int* batch       = (const int*)d_in[20];
    float* out = (float*)d_out;

    char* p = (char*)d_ws;
    auto carve = [&](size_t bytes) -> char* {
        char* r = p; p += (bytes + 255) & ~(size_t)255; return r;
    };
    // total ~229 MB
    ushortT* Wt0   = (ushortT*)carve((size_t)HID * EMB * 2);
    ushortT* Wt1   = (ushortT*)carve((size_t)HID * HID * 2);
    ushortT* Wt2   = (ushortT*)carve((size_t)HID * HID * 2);
    ushortT* xpb   = (ushortT*)carve((size_t)AP * EMB * 2);
    ushortT* xha   = (ushortT*)carve((size_t)AP * HID * 2);
    ushortT* hbf   = (ushortT*)carve((size_t)MP * HID * 2);
    ushortT* xhb   = (ushortT*)carve((size_t)MP * HID * 2);
    float*   ssrc  = (float*)carve((size_t)MP * NH * 4);
    float*   sdstb = (float*)carve((size_t)MP * NH * 4);
    float*   ssrca = (float*)carve((size_t)AP * NH * 4);
    float*   sdsta = (float*)carve((size_t)AP * NH * 4);
    float*   pq    = (float*)carve(NL * NH * 2 * 4);
    float*   meana = (float*)carve(256);
    float*   pqpart= (float*)carve((size_t)16 * 12 * 2 * 4);
    float*   mpart = (float*)carve(64 * 4);
    int*     cntdeg= (int*)carve((size_t)NSUB * 4);
    int*     rs    = (int*)carve((size_t)(NSUB + 1) * 4);
    int*     cursor= (int*)carve((size_t)NSUB * 4);
    int*     esrcPS= (int*)carve((size_t)ETOT * 4);
    int*     esrcPA= (int*)carve((size_t)ETOT * 4);
    float*   eafP  = (float*)carve((size_t)ETOT * 4);
    int*     cnt2  = (int*)carve((size_t)N_ATOMS * 4);
    int*     rs2   = (int*)carve((size_t)(N_ATOMS + 1) * 4);
    int*     cur2  = (int*)carve((size_t)N_ATOMS * 4);
    int*     ids2  = (int*)carve((size_t)NSUB * 4);
    int*     bstart= (int*)carve(NBATCH * 4);
    int*     bend  = (int*)carve(NBATCH * 4);
    float*   pa    = (float*)carve((size_t)NBATCH * HID * 4);
    float*   part  = (float*)carve((size_t)16 * NBATCH * HID * 4);
    float*   agg   = (float*)xhb;  // overlay: xhb dead after last k_attn

    // per-call zero-init (pad-row memsets removed: pad rows are never read)
    (void)hipMemsetAsync(cntdeg, 0, (size_t)NSUB * 4, stream);
    (void)hipMemsetAsync(cursor, 0, (size_t)NSUB * 4, stream);
    (void)hipMemsetAsync(cnt2, 0, (size_t)N_ATOMS * 4, stream);
    (void)hipMemsetAsync(cur2, 0, (size_t)N_ATOMS * 4, stream);
    (void)hipMemsetAsync(bstart, 0x7f, NBATCH * 4, stream);
    (void)hipMemsetAsync(bend, 0, NBATCH * 4, stream);

    dim3 tb(32, 8);
    k_cast3<<<dim3(HID / 32, HID / 32, 3), tb, 0, stream>>>(W0, Ws, Wt0, Wt1, Wt2);
    k_node_proj<<<N_ATOMS / NPB, 256, 0, stream>>>(x, Wn, bn, xpb);
    k_mean_part<<<64, 256, 0, stream>>>(ea, mpart);
    k_pq_part<<<dim3(NL * NH, 16), 256, 0, stream>>>(We, be, W_edge, att_edge, pqpart);
    k_pq_red<<<1, 64, 0, stream>>>(pqpart, mpart, pq, meana);

    const int* dsti = sei + NEDGE;
    k_counts<<<(ETOT + NSUB + N_ATOMS + 255) / 256, 256, 0, stream>>>(
        dsti, sind, batch, cntdeg, cnt2, bstart, bend);
    k_scan<<<1, 1024, 0, stream>>>(cntdeg, rs, NSUB);
    k_scan<<<1, 1024, 0, stream>>>(cnt2, rs2, N_ATOMS);
    k_fills<<<(ETOT + NSUB + 255) / 256, 256, 0, stream>>>(
        dsti, sei, sni, ea, meana, sind, rs, rs2, cursor, cur2,
        esrcPS, esrcPA, eafP, ids2);

    // ---- layer 0 at atom level ----
    k_gemm<<<dim3(AP / 128, HID / 128), 256, 0, stream>>>(xpb, Wt0, xha, EMB);
    k_sdots<<<N_ATOMS, 256, 0, stream>>>(xha, att_src, att_dst, ssrca, sdsta, 0);
    k_attn<<<NSUB / 4, 256, 0, stream>>>(xha, ssrca, sdsta, rs, esrcPA, eafP, pq,
                                         conv_bias, gammav, betav, hbf, 0, sni);

    // ---- layers 1..2 on subgraph domain ----
    for (int l = 1; l < NL; ++l) {
        const ushortT* Wt = (l == 1) ? Wt1 : Wt2;
        k_gemm<<<dim3(MP / 128, HID / 128), 256, 0, stream>>>(hbf, Wt, xhb, HID);
        k_sdots<<<NSUB, 256, 0, stream>>>(xhb, att_src, att_dst, ssrc, sdstb, l);
        k_attn<<<NSUB / 4, 256, 0, stream>>>(xhb, ssrc, sdstb, rs, esrcPS, eafP, pq,
                                             conv_bias, gammav, betav, hbf, l, (const int*)nullptr);
    }

    k_agg<<<N_ATOMS, 256, 0, stream>>>(hbf, rs2, ids2, agg);
    k_pool<<<dim3(NBATCH, HID / 128), 128, 0, stream>>>(agg, bstart, bend, pa);
    k_fpart<<<dim3(16, HID / 256), 256, 0, stream>>>(pa, Wf, part);
    k_fred<<<dim3(NBATCH, HID / 256), 256, 0, stream>>>(part, bfv, bstart, bend, out);
}

// Round 15
// 937.577 us; speedup vs baseline: 1.0635x; 1.0208x over previous
//
#include <hip/hip_runtime.h>

typedef unsigned short ushortT;
typedef __attribute__((ext_vector_type(4))) float f32x4;
typedef __attribute__((ext_vector_type(8))) short bf16x8;
typedef __attribute__((ext_vector_type(4))) unsigned int u32x4;
typedef __attribute__((ext_vector_type(4))) unsigned short u16x4;

#define N_ATOMS 6000
#define NSUB    20000
#define NEDGE   60000
#define NBATCH  16
#define INDIM   78
#define EMB     1024
#define HID     2048
#define NH      4
#define CH      512
#define NL      3
#define MP      20096          // NSUB padded to multiple of 128
#define AP      6016           // N_ATOMS padded to multiple of 128
#define ETOT    (NEDGE + NSUB) // edges + self loops
#define NPB     8              // atoms per block in k_node_proj

#define GLOAD_LDS16(gp, lp) \
    __builtin_amdgcn_global_load_lds((const __attribute__((address_space(1))) void*)(gp), \
                                     (__attribute__((address_space(3))) void*)(lp), 16, 0, 0)

__device__ __forceinline__ ushortT f2bf(float x) {
    union { float f; unsigned u; } v; v.f = x;
    unsigned r = v.u + 0x7fffu + ((v.u >> 16) & 1u);   // RNE
    return (ushortT)(r >> 16);
}
__device__ __forceinline__ float bf2f(ushortT h) {
    union { unsigned u; float f; } v; v.u = ((unsigned)h) << 16; return v.f;
}

// ---------- init: mean partials (blocks 0-63, same partition as before) +
//            counter zeroing / batch-range init (blocks 64+) ----------
__global__ void k_init(const float* __restrict__ ea, float* __restrict__ mpart,
                       int* __restrict__ cntdeg, int* __restrict__ cursor,
                       int* __restrict__ cnt2, int* __restrict__ cur2,
                       int* __restrict__ bstart, int* __restrict__ bend) {
    int b = blockIdx.x;
    if (b < 64) {
        __shared__ float red[256];
        float s = 0;
        for (int i = b * 256 + threadIdx.x; i < NEDGE; i += 64 * 256) s += ea[i];
        red[threadIdx.x] = s; __syncthreads();
        for (int d = 128; d > 0; d >>= 1) {
            if (threadIdx.x < d) red[threadIdx.x] += red[threadIdx.x + d];
            __syncthreads();
        }
        if (threadIdx.x == 0) mpart[b] = red[0];
    } else {
        int i = (b - 64) * 256 + threadIdx.x;
        if (i < NSUB) { cntdeg[i] = 0; cursor[i] = 0; }
        if (i < N_ATOMS) { cnt2[i] = 0; cur2[i] = 0; }
        if (i < NBATCH) { bstart[i] = 0x7f7f7f7f; bend[i] = 0; }
    }
}

// ---------- weight cast + transpose, all three matrices in one launch ----------
__global__ void k_cast3(const float* __restrict__ W0, const float* __restrict__ Ws,
                        ushortT* __restrict__ Wt0, ushortT* __restrict__ Wt1,
                        ushortT* __restrict__ Wt2) {
    __shared__ float tile[32][33];
    int z = blockIdx.z;
    const float* W = (z == 0) ? W0 : (z == 1 ? Ws : Ws + (size_t)HID * HID);
    ushortT* Wt = (z == 0) ? Wt0 : (z == 1 ? Wt1 : Wt2);
    int K = (z == 0) ? EMB : HID;
    int n0 = blockIdx.x * 32, k0 = blockIdx.y * 32;
    if (k0 >= K) return;
    int tx = threadIdx.x, ty = threadIdx.y; // 32 x 8
    for (int i = 0; i < 32; i += 8)
        tile[ty + i][tx] = W[(size_t)(k0 + ty + i) * HID + n0 + tx];
    __syncthreads();
    for (int i = 0; i < 32; i += 8)
        Wt[(size_t)(n0 + ty + i) * K + k0 + tx] = f2bf(tile[tx][ty + i]);
}

// ---------- node projection: xpb = bf16(x @ Wn + bn), 8 atoms/block ----------
__global__ __launch_bounds__(256) void k_node_proj(const float* __restrict__ x,
                                                   const float* __restrict__ Wn,
                                                   const float* __restrict__ bn,
                                                   ushortT* __restrict__ xpb) {
    int n0 = blockIdx.x * NPB;
    __shared__ float xr[NPB][INDIM];
    int tid = threadIdx.x;
    for (int i = tid; i < NPB * INDIM; i += 256)
        xr[i / INDIM][i % INDIM] = x[(size_t)(n0 + i / INDIM) * INDIM + (i % INDIM)];
    __syncthreads();
    for (int j = tid; j < EMB; j += 256) {
        float acc[NPB];
        float b = bn[j];
        #pragma unroll
        for (int a = 0; a < NPB; ++a) acc[a] = b;
        #pragma unroll 6
        for (int k = 0; k < INDIM; ++k) {
            float wv = Wn[(size_t)k * EMB + j];
            #pragma unroll
            for (int a = 0; a < NPB; ++a) acc[a] += xr[a][k] * wv;
        }
        #pragma unroll
        for (int a = 0; a < NPB; ++a)
            xpb[(size_t)(n0 + a) * EMB + j] = f2bf(acc[a]);
    }
}

// ---------- edge-attention scalars p,q: split-K partials (12 x 16 blocks) ----------
__global__ __launch_bounds__(256) void k_pq_part(const float* __restrict__ We,
                                                 const float* __restrict__ be,
                                                 const float* __restrict__ W_edge,
                                                 const float* __restrict__ att_edge,
                                                 float* __restrict__ part) {
    int l = blockIdx.x >> 2, h = blockIdx.x & 3;
    int k0 = blockIdx.y * 64;
    const float* Wl = W_edge + (size_t)l * EMB * HID + h * CH;
    const float* ae = att_edge + ((size_t)l * NH + h) * CH;
    int tid = threadIdx.x;
    float aP0 = 0, aP1 = 0, aQ0 = 0, aQ1 = 0;
    #pragma unroll 4
    for (int k = k0; k < k0 + 64; ++k) {
        float wek = We[k], bek = be[k];
        float w0 = Wl[(size_t)k * HID + tid];
        float w1 = Wl[(size_t)k * HID + tid + 256];
        aP0 += wek * w0; aP1 += wek * w1;
        aQ0 += bek * w0; aQ1 += bek * w1;
    }
    float p = aP0 * ae[tid] + aP1 * ae[tid + 256];
    float q = aQ0 * ae[tid] + aQ1 * ae[tid + 256];
    __shared__ float rp[256], rq[256];
    rp[tid] = p; rq[tid] = q; __syncthreads();
    for (int d = 128; d > 0; d >>= 1) {
        if (tid < d) { rp[tid] += rp[tid + d]; rq[tid] += rq[tid + d]; }
        __syncthreads();
    }
    if (tid == 0) {
        part[((size_t)blockIdx.y * 12 + blockIdx.x) * 2]     = rp[0];
        part[((size_t)blockIdx.y * 12 + blockIdx.x) * 2 + 1] = rq[0];
    }
}

// ---------- pq + mean final reduce (fixed order, deterministic) ----------
__global__ void k_pq_red(const float* __restrict__ part, const float* __restrict__ mpart,
                         float* __restrict__ pq, float* __restrict__ meana) {
    int t = threadIdx.x;
    if (t < 24) {
        float s = 0;
        for (int kc = 0; kc < 16; ++kc) s += part[((size_t)kc * 12 + (t >> 1)) * 2 + (t & 1)];
        pq[t] = s;
    }
    if (t == 32) {
        float s = 0;
        for (int i = 0; i < 64; ++i) s += mpart[i];
        meana[0] = s / (float)NEDGE;
    }
}

// ---------- merged counters: edge-degree + subgraph-indicator + batch ranges ----------
__global__ void k_counts(const int* __restrict__ dsti, const int* __restrict__ sind,
                         const int* __restrict__ batch,
                         int* __restrict__ cntdeg, int* __restrict__ cnt2,
                         int* __restrict__ bstart, int* __restrict__ bend) {
    int t = blockIdx.x * 256 + threadIdx.x;
    if (t < ETOT) {
        int d = (t < NEDGE) ? dsti[t] : (t - NEDGE);
        atomicAdd(&cntdeg[d], 1);
    } else if (t < ETOT + NSUB) {
        atomicAdd(&cnt2[sind[t - ETOT]], 1);
    } else if (t < ETOT + NSUB + N_ATOMS) {
        int a = t - ETOT - NSUB;
        int b = batch[a];
        atomicMin(&bstart[b], a);
        atomicMax(&bend[b], a + 1);
    }
}

// ---------- dual exclusive scan: block 0 -> rs (NSUB), block 1 -> rs2 (N_ATOMS) ----
__global__ void k_scan2(const int* __restrict__ cntdeg, int* __restrict__ rs,
                        const int* __restrict__ cnt2, int* __restrict__ rs2) {
    const int* cnt = (blockIdx.x == 0) ? cntdeg : cnt2;
    int* out = (blockIdx.x == 0) ? rs : rs2;
    const int n = (blockIdx.x == 0) ? NSUB : N_ATOMS;
    __shared__ int part[1024];
    int tid = threadIdx.x;
    const int per = (n + 1023) / 1024;
    int base = tid * per;
    int s = 0;
    for (int i = 0; i < per; ++i) { int idx = base + i; if (idx < n) s += cnt[idx]; }
    part[tid] = s;
    __syncthreads();
    for (int d = 1; d < 1024; d <<= 1) {
        int v = (tid >= d) ? part[tid - d] : 0;
        __syncthreads();
        part[tid] += v;
        __syncthreads();
    }
    int off = part[tid] - s; // exclusive
    for (int i = 0; i < per; ++i) {
        int idx = base + i;
        if (idx < n) { out[idx] = off; off += cnt[idx]; }
    }
    if (tid == 1023) out[n] = part[1023];
}

// ---------- merged fills: CSR edge fill (pos-ordered src/attr) + indicator fill ----
__global__ void k_fills(const int* __restrict__ dsti, const int* __restrict__ srci,
                        const int* __restrict__ sni, const float* __restrict__ ea,
                        const float* __restrict__ meana, const int* __restrict__ sind,
                        const int* __restrict__ rs, const int* __restrict__ rs2,
                        int* __restrict__ cursor, int* __restrict__ cur2,
                        int* __restrict__ esrcPS, int* __restrict__ esrcPA,
                        float* __restrict__ eafP, int* __restrict__ ids2) {
    int t = blockIdx.x * 256 + threadIdx.x;
    if (t < ETOT) {
        int d, s; float a;
        if (t < NEDGE) { d = dsti[t]; s = srci[t]; a = ea[t]; }
        else           { d = t - NEDGE; s = d;     a = meana[0]; }
        int pos = rs[d] + atomicAdd(&cursor[d], 1);
        esrcPS[pos] = s;
        esrcPA[pos] = sni[s];
        eafP[pos] = a;
    } else if (t < ETOT + NSUB) {
        int i = t - ETOT;
        int aT = sind[i];
        int pos = rs2[aT] + atomicAdd(&cur2[aT], 1);
        ids2[pos] = i;
    }
}

// ---------- bf16 MFMA GEMM (proven 869 TF): gload_lds + involution swizzle ----------
__global__ __launch_bounds__(256) void k_gemm(const ushortT* __restrict__ A,
                                              const ushortT* __restrict__ Bt,
                                              ushortT* __restrict__ Cb, int K) {
    __shared__ alignas(16) ushortT As[128 * 64];   // 16 KB
    __shared__ alignas(16) ushortT Bs[128 * 64];   // 16 KB
    const int tid = threadIdx.x;
    const int nx = (int)gridDim.x;                 // bm tiles
    const int ny = (int)gridDim.y;                 // 16  (bn tiles)
    int o = (int)blockIdx.y * nx + (int)blockIdx.x;  // dispatch order (bx fast)
    int cpx = (nx * ny) >> 3;                        // blocks per XCD
    int s = (o & 7) * cpx + (o >> 3);                // sequential id within XCD span
    const int bm = s / ny, bn = s % ny;              // bn fast -> A-panel reuse
    const int wave = tid >> 6, lane = tid & 63;
    const int wr = wave >> 1, wc = wave & 1;
    f32x4 acc[4][4] = {};
    const int frow = lane & 15;          // fragment row within 16
    const int cb0  = lane >> 4;          // k col-block 0..3 (8 elems each)
    const ushortT* Ab = A + (size_t)bm * 128 * K;
    const ushortT* Bb = Bt + (size_t)bn * 128 * K;
    const int srow = (lane >> 3);                        // 0..7 within chunk
    const int sswz = (((lane & 7) ^ srow) << 3);         // swizzled elem col
    for (int k0 = 0; k0 < K; k0 += 64) {
        #pragma unroll
        for (int i = 0; i < 4; ++i) {
            int c = wave * 4 + i;                        // chunk 0..15
            int r = c * 8 + srow;                        // tile row 0..127
            GLOAD_LDS16(Ab + (size_t)r * K + k0 + sswz, As + c * 512 + lane * 8);
            GLOAD_LDS16(Bb + (size_t)r * K + k0 + sswz, Bs + c * 512 + lane * 8);
        }
        __syncthreads();
        #pragma unroll
        for (int kk = 0; kk < 64; kk += 32) {
            bf16x8 af[4], bfr[4];
            #pragma unroll
            for (int m = 0; m < 4; ++m) {
                int row = wr * 64 + m * 16 + frow;
                int cb = (kk >> 3) + cb0;
                af[m] = *(const bf16x8*)&As[row * 64 + ((cb ^ (frow & 7)) << 3)];
            }
            #pragma unroll
            for (int n = 0; n < 4; ++n) {
                int row = wc * 64 + n * 16 + frow;
                int cb = (kk >> 3) + cb0;
                bfr[n] = *(const bf16x8*)&Bs[row * 64 + ((cb ^ (frow & 7)) << 3)];
            }
            #pragma unroll
            for (int m = 0; m < 4; ++m)
                #pragma unroll
                for (int n = 0; n < 4; ++n)
                    acc[m][n] = __builtin_amdgcn_mfma_f32_16x16x32_bf16(af[m], bfr[n], acc[m][n], 0, 0, 0);
        }
        __syncthreads();
    }
    const int cr = (lane >> 4) * 4;
    const int cc = lane & 15;
    #pragma unroll
    for (int m = 0; m < 4; ++m)
        #pragma unroll
        for (int n = 0; n < 4; ++n)
            #pragma unroll
            for (int r = 0; r < 4; ++r) {
                size_t row = (size_t)bm * 128 + wr * 64 + m * 16 + cr + r;
                int col = bn * 128 + wc * 64 + n * 16 + cc;
                Cb[row * HID + col] = f2bf(acc[m][n][r]);
            }
}

// ---------- per-(node,head) attention dot scalars (bf16 xh) ----------
__global__ __launch_bounds__(256) void k_sdots(const ushortT* __restrict__ xh,
                                               const float* __restrict__ att_src,
                                               const float* __restrict__ att_dst,
                                               float* __restrict__ ssrc,
                                               float* __restrict__ sdst, int layer) {
    int n = blockIdx.x;
    int h = threadIdx.x >> 6, lane = threadIdx.x & 63;
    const ushortT* row = xh + (size_t)n * HID + h * CH + lane * 8;
    const float* as = att_src + ((size_t)layer * NH + h) * CH + lane * 8;
    const float* ad = att_dst + ((size_t)layer * NH + h) * CH + lane * 8;
    u16x4 v0 = *(const u16x4*)row, v1 = *(const u16x4*)(row + 4);
    f32x4 a0 = *(const f32x4*)as, a1 = *(const f32x4*)(as + 4);
    f32x4 d0 = *(const f32x4*)ad, d1 = *(const f32x4*)(ad + 4);
    float ps = 0.f, pd = 0.f;
    #pragma unroll
    for (int t = 0; t < 4; ++t) {
        float f0 = bf2f(v0[t]), f1 = bf2f(v1[t]);
        ps += f0 * a0[t] + f1 * a1[t];
        pd += f0 * d0[t] + f1 * d1[t];
    }
    #pragma unroll
    for (int d = 32; d > 0; d >>= 1) { ps += __shfl_down(ps, d); pd += __shfl_down(pd, d); }
    if (lane == 0) { ssrc[n * NH + h] = ps; sdst[n * NH + h] = pd; }
}

// ---------- fused attention: one wave per dst, CSR-ordered edge data ----------
__global__ __launch_bounds__(256) void k_attn(const ushortT* __restrict__ xh,
                                              const float* __restrict__ ssrc,
                                              const float* __restrict__ sdst,
                                              const int* __restrict__ rs,
                                              const int* __restrict__ esrcP,
                                              const float* __restrict__ eafP,
                                              const float* __restrict__ pq,
                                              const float* __restrict__ conv_bias,
                                              const float* __restrict__ gammav,
                                              const float* __restrict__ betav,
                                              ushortT* __restrict__ hout, int layer,
                                              const int* __restrict__ nmap) {
    int wv = threadIdx.x >> 6, lane = threadIdx.x & 63;
    int n = blockIdx.x * 4 + wv;       // NSUB = 5000 blocks * 4 waves, exact
    int nn = nmap ? nmap[n] : n;
    int beg = rs[n], end = rs[n + 1];
    f32x4 pq01 = *(const f32x4*)&pq[layer * 8];
    f32x4 pq23 = *(const f32x4*)&pq[layer * 8 + 4];
    float px[NH] = {pq01[0], pq01[2], pq23[0], pq23[2]};
    float qx[NH] = {pq01[1], pq01[3], pq23[1], pq23[3]};
    f32x4 sdv = *(const f32x4*)&sdst[nn * NH];
    float m[NH], z[NH];
    #pragma unroll
    for (int h = 0; h < NH; ++h) { m[h] = -INFINITY; z[h] = 0.f; }
    float facc[NH][8] = {};
    for (int pos = beg; pos < end; ++pos) {
        int s = esrcP[pos];
        float a = eafP[pos];
        f32x4 ssv = *(const f32x4*)&ssrc[s * NH];
        const ushortT* xr = xh + (size_t)s * HID + lane * 8;
        #pragma unroll
        for (int h = 0; h < NH; ++h) {
            float logit = ssv[h] + sdv[h] + a * px[h] + qx[h];
            logit = (logit > 0.f) ? logit : 0.2f * logit;
            float mn = fmaxf(m[h], logit);
            float scale = expf(m[h] - mn);   // 0 when m == -inf
            float w = expf(logit - mn);
            z[h] = z[h] * scale + w;
            bf16x8 u = *(const bf16x8*)(xr + h * CH);
            #pragma unroll
            for (int j = 0; j < 8; ++j)
                facc[h][j] = facc[h][j] * scale + w * bf2f((ushortT)u[j]);
            m[h] = mn;
        }
    }
    // bias + LN stats over the wave's 2048 channels (32 per lane)
    float val[NH][8];
    float s1 = 0.f, s2 = 0.f;
    #pragma unroll
    for (int h = 0; h < NH; ++h) {
        float inv = 1.f / (z[h] + 1e-16f);
        int cb = h * CH + lane * 8;
        f32x4 b0 = *(const f32x4*)&conv_bias[layer * HID + cb];
        f32x4 b1 = *(const f32x4*)&conv_bias[layer * HID + cb + 4];
        #pragma unroll
        for (int j = 0; j < 4; ++j) {
            float v0 = facc[h][j] * inv + b0[j];
            float v1 = facc[h][4 + j] * inv + b1[j];
            val[h][j] = v0; val[h][4 + j] = v1;
            s1 += v0 + v1; s2 += v0 * v0 + v1 * v1;
        }
    }
    #pragma unroll
    for (int d = 32; d > 0; d >>= 1) { s1 += __shfl_xor(s1, d); s2 += __shfl_xor(s2, d); }
    float mu = s1 / (float)HID;
    float var = s2 / (float)HID - mu * mu;
    float rstd = rsqrtf(var + 1e-5f);
    #pragma unroll
    for (int h = 0; h < NH; ++h) {
        int cb = h * CH + lane * 8;
        f32x4 g0 = *(const f32x4*)&gammav[layer * HID + cb];
        f32x4 g1 = *(const f32x4*)&gammav[layer * HID + cb + 4];
        f32x4 e0 = *(const f32x4*)&betav[layer * HID + cb];
        f32x4 e1 = *(const f32x4*)&betav[layer * HID + cb + 4];
        u16x4 o0, o1;
        #pragma unroll
        for (int j = 0; j < 4; ++j) {
            float y0 = (val[h][j] - mu) * rstd * g0[j] + e0[j];
            float y1 = (val[h][4 + j] - mu) * rstd * g1[j] + e1[j];
            o0[j] = f2bf(fmaxf(y0, 0.f));
            o1[j] = f2bf(fmaxf(y1, 0.f));
        }
        *(u16x4*)&hout[(size_t)n * HID + cb]     = o0;
        *(u16x4*)&hout[(size_t)n * HID + cb + 4] = o1;
    }
}

// ---------- subgraph -> atom aggregation via CSR gather (no atomics) ----------
__global__ __launch_bounds__(256) void k_agg(const ushortT* __restrict__ hbf,
                                             const int* __restrict__ rs2,
                                             const int* __restrict__ ids2,
                                             float* __restrict__ agg) {
    int a = blockIdx.x;
    int beg = rs2[a], end = rs2[a + 1];
    int col = threadIdx.x * 8;
    float acc[8] = {0,0,0,0,0,0,0,0};
    for (int pos = beg; pos < end; ++pos) {
        int i = ids2[pos];
        const u16x4* ptr = (const u16x4*)(hbf + (size_t)i * HID + col);
        u16x4 h0 = ptr[0], h1 = ptr[1];
        #pragma unroll
        for (int t = 0; t < 4; ++t) { acc[t] += bf2f(h0[t]); acc[4 + t] += bf2f(h1[t]); }
    }
    int cnt = end - beg;
    float inv = 1.f / (float)(cnt > 1 ? cnt : 1);
    f32x4 o0, o1;
    #pragma unroll
    for (int t = 0; t < 4; ++t) { o0[t] = acc[t] * inv; o1[t] = acc[4 + t] * inv; }
    float* dst = agg + (size_t)a * HID + col;
    *(f32x4*)dst = o0;
    *(f32x4*)(dst + 4) = o1;
}

// ---------- per-molecule mean of atom aggregates ----------
__global__ __launch_bounds__(128) void k_pool(const float* __restrict__ agg,
                                              const int* __restrict__ bstart,
                                              const int* __restrict__ bend,
                                              float* __restrict__ pa) {
    int b = blockIdx.x;
    int col = blockIdx.y * 128 + threadIdx.x;
    int s = bstart[b], e = bend[b];
    float v = 0.f;
    for (int a = s; a < e; ++a) v += agg[(size_t)a * HID + col];
    int g = e - s;
    pa[b * HID + col] = (g > 0) ? v / (float)g : 0.f;
}

// ---------- final projection, split-K pass 1: part[kc][b][col] ----------
__global__ __launch_bounds__(256) void k_fpart(const float* __restrict__ pa,
                                               const float* __restrict__ Wf,
                                               float* __restrict__ part) {
    int kc = blockIdx.x;            // 16 k-chunks of 128
    int col = blockIdx.y * 256 + threadIdx.x;
    int k0 = kc * 128;
    __shared__ float pl[NBATCH][128];
    for (int i = threadIdx.x; i < NBATCH * 128; i += 256) {
        int b = i >> 7, k = i & 127;
        pl[b][k] = pa[b * HID + k0 + k];
    }
    __syncthreads();
    float acc[NBATCH];
    #pragma unroll
    for (int b = 0; b < NBATCH; ++b) acc[b] = 0.f;
    for (int kk = 0; kk < 128; kk += 4) {
        f32x4 w;
        #pragma unroll
        for (int u = 0; u < 4; ++u) w[u] = Wf[(size_t)(k0 + kk + u) * HID + col];
        #pragma unroll
        for (int b = 0; b < NBATCH; ++b) {
            f32x4 pv = *(const f32x4*)&pl[b][kk];
            acc[b] += pv[0] * w[0] + pv[1] * w[1] + pv[2] * w[2] + pv[3] * w[3];
        }
    }
    #pragma unroll
    for (int b = 0; b < NBATCH; ++b)
        part[((size_t)kc * NBATCH + b) * HID + col] = acc[b];
}

// ---------- final projection, pass 2: deterministic reduce + bias ----------
__global__ __launch_bounds__(256) void k_fred(const float* __restrict__ part,
                                              const float* __restrict__ bfv,
                                              const int* __restrict__ bstart,
                                              const int* __restrict__ bend,
                                              float* __restrict__ out) {
    int b = blockIdx.x;
    int col = blockIdx.y * 256 + threadIdx.x;
    float s = 0.f;
    #pragma unroll
    for (int kc = 0; kc < 16; ++kc)
        s += part[((size_t)kc * NBATCH + b) * HID + col];
    int g = bend[b] - bstart[b];
    out[b * HID + col] = (g > 0) ? s + bfv[col] : 0.f;
}

extern "C" void kernel_launch(void* const* d_in, const int* in_sizes, int n_in,
                              void* d_out, int out_size, void* d_ws, size_t ws_size,
                              hipStream_t stream) {
    const float* x         = (const float*)d_in[0];
    const float* ea        = (const float*)d_in[1];
    const float* Wn        = (const float*)d_in[2];
    const float* bn        = (const float*)d_in[3];
    const float* We        = (const float*)d_in[4];
    const float* be        = (const float*)d_in[5];
    const float* W0        = (const float*)d_in[6];
    const float* Ws        = (const float*)d_in[7];
    const float* att_src   = (const float*)d_in[8];
    const float* att_dst   = (const float*)d_in[9];
    const float* att_edge  = (const float*)d_in[10];
    const float* W_edge    = (const float*)d_in[11];
    const float* conv_bias = (const float*)d_in[12];
    const float* gammav    = (const float*)d_in[13];
    const float* betav     = (const float*)d_in[14];
    const float* Wf        = (const float*)d_in[15];
    const float* bfv       = (const float*)d_in[16];
    const int* sni         = (const int*)d_in[17];
    const int* sei         = (const int*)d_in[18];
    const int* sind        = (const int*)d_in[19];
    const int* batch       = (const int*)d_in[20];
    float* out = (float*)d_out;

    char* p = (char*)d_ws;
    auto carve = [&](size_t bytes) -> char* {
        char* r = p; p += (bytes + 255) & ~(size_t)255; return r;
    };
    // total ~229 MB
    ushortT* Wt0   = (ushortT*)carve((size_t)HID * EMB * 2);
    ushortT* Wt1   = (ushortT*)carve((size_t)HID * HID * 2);
    ushortT* Wt2   = (ushortT*)carve((size_t)HID * HID * 2);
    ushortT* xpb   = (ushortT*)carve((size_t)AP * EMB * 2);
    ushortT* xha   = (ushortT*)carve((size_t)AP * HID * 2);
    ushortT* hbf   = (ushortT*)carve((size_t)MP * HID * 2);
    ushortT* xhb   = (ushortT*)carve((size_t)MP * HID * 2);
    float*   ssrc  = (float*)carve((size_t)MP * NH * 4);
    float*   sdstb = (float*)carve((size_t)MP * NH * 4);
    float*   ssrca = (float*)carve((size_t)AP * NH * 4);
    float*   sdsta = (float*)carve((size_t)AP * NH * 4);
    float*   pq    = (float*)carve(NL * NH * 2 * 4);
    float*   meana = (float*)carve(256);
    float*   pqpart= (float*)carve((size_t)16 * 12 * 2 * 4);
    float*   mpart = (float*)carve(64 * 4);
    int*     cntdeg= (int*)carve((size_t)NSUB * 4);
    int*     rs    = (int*)carve((size_t)(NSUB + 1) * 4);
    int*     cursor= (int*)carve((size_t)NSUB * 4);
    int*     esrcPS= (int*)carve((size_t)ETOT * 4);
    int*     esrcPA= (int*)carve((size_t)ETOT * 4);
    float*   eafP  = (float*)carve((size_t)ETOT * 4);
    int*     cnt2  = (int*)carve((size_t)N_ATOMS * 4);
    int*     rs2   = (int*)carve((size_t)(N_ATOMS + 1) * 4);
    int*     cur2  = (int*)carve((size_t)N_ATOMS * 4);
    int*     ids2  = (int*)carve((size_t)NSUB * 4);
    int*     bstart= (int*)carve(NBATCH * 4);
    int*     bend  = (int*)carve(NBATCH * 4);
    float*   pa    = (float*)carve((size_t)NBATCH * HID * 4);
    float*   part  = (float*)carve((size_t)16 * NBATCH * HID * 4);
    float*   agg   = (float*)xhb;  // overlay: xhb dead after last k_attn

    dim3 tb(32, 8);
    k_init<<<64 + (NSUB + 255) / 256, 256, 0, stream>>>(ea, mpart, cntdeg, cursor,
                                                        cnt2, cur2, bstart, bend);
    k_cast3<<<dim3(HID / 32, HID / 32, 3), tb, 0, stream>>>(W0, Ws, Wt0, Wt1, Wt2);
    k_node_proj<<<N_ATOMS / NPB, 256, 0, stream>>>(x, Wn, bn, xpb);
    k_pq_part<<<dim3(NL * NH, 16), 256, 0, stream>>>(We, be, W_edge, att_edge, pqpart);
    k_pq_red<<<1, 64, 0, stream>>>(pqpart, mpart, pq, meana);

    const int* dsti = sei + NEDGE;
    k_counts<<<(ETOT + NSUB + N_ATOMS + 255) / 256, 256, 0, stream>>>(
        dsti, sind, batch, cntdeg, cnt2, bstart, bend);
    k_scan2<<<2, 1024, 0, stream>>>(cntdeg, rs, cnt2, rs2);
    k_fills<<<(ETOT + NSUB + 255) / 256, 256, 0, stream>>>(
        dsti, sei, sni, ea, meana, sind, rs, rs2, cursor, cur2,
        esrcPS, esrcPA, eafP, ids2);

    // ---- layer 0 at atom level ----
    k_gemm<<<dim3(AP / 128, HID / 128), 256, 0, stream>>>(xpb, Wt0, xha, EMB);
    k_sdots<<<N_ATOMS, 256, 0, stream>>>(xha, att_src, att_dst, ssrca, sdsta, 0);
    k_attn<<<NSUB / 4, 256, 0, stream>>>(xha, ssrca, sdsta, rs, esrcPA, eafP, pq,
                                         conv_bias, gammav, betav, hbf, 0, sni);

    // ---- layers 1..2 on subgraph domain ----
    for (int l = 1; l < NL; ++l) {
        const ushortT* Wt = (l == 1) ? Wt1 : Wt2;
        k_gemm<<<dim3(MP / 128, HID / 128), 256, 0, stream>>>(hbf, Wt, xhb, HID);
        k_sdots<<<NSUB, 256, 0, stream>>>(xhb, att_src, att_dst, ssrc, sdstb, l);
        k_attn<<<NSUB / 4, 256, 0, stream>>>(xhb, ssrc, sdstb, rs, esrcPS, eafP, pq,
                                             conv_bias, gammav, betav, hbf, l, (const int*)nullptr);
    }

    k_agg<<<N_ATOMS, 256, 0, stream>>>(hbf, rs2, ids2, agg);
    k_pool<<<dim3(NBATCH, HID / 128), 128, 0, stream>>>(agg, bstart, bend, pa);
    k_fpart<<<dim3(16, HID / 256), 256, 0, stream>>>(pa, Wf, part);
    k_fred<<<dim3(NBATCH, HID / 256), 256, 0, stream>>>(part, bfv, bstart, bend, out);
}